// Round 17
// baseline (403.277 us; speedup 1.0000x reference)
//
#include <hip/hip_runtime.h>
#include <hip/hip_bf16.h>
#include <math.h>

#define BB 64
#define TT 128
#define T1 127
#define NNODE 2000
#define EE 300
#define HID 256
#define NHEADS 5
#define DD 16
#define G3 768
#define ATT 1280
#define SCALE_H 28.0f

typedef _Float16 h2_t __attribute__((ext_vector_type(2)));
typedef short short8 __attribute__((ext_vector_type(8)));
typedef float f32x4 __attribute__((ext_vector_type(4)));

__device__ __forceinline__ int dot4(int a, int b, int c) {
#if __has_builtin(__builtin_amdgcn_sdot4)
    return __builtin_amdgcn_sdot4(a, b, c, false);
#else
    int r;
    asm("v_dot4_i32_i8 %0, %1, %2, %3" : "=v"(r) : "v"(a), "v"(b), "v"(c));
    return r;
#endif
}

__device__ __forceinline__ unsigned short f2bf(float f) {
    unsigned u = __float_as_uint(f);
    unsigned r = (u + 0x7FFFu + ((u >> 16) & 1u)) >> 16;   // RNE
    return (unsigned short)r;
}

__device__ __forceinline__ float bf2f(unsigned short u) {
    return __uint_as_float((unsigned)u << 16);
}

// ---------------- merged transpose + f32->bf16 (w_ih and ws1 in one launch) ----------------
__global__ void k_tcvt2(const float* __restrict__ a, unsigned short* __restrict__ da, int Ra, int Ca,
                        const float* __restrict__ b, unsigned short* __restrict__ db, int Rb, int Cb) {
    int idx = blockIdx.x * 256 + threadIdx.x;
    int na = Ra * Ca;
    if (idx < na) {
        int r = idx / Ca, c = idx % Ca;
        da[c * Ra + r] = f2bf(a[idx]);
    } else {
        idx -= na;
        if (idx < Rb * Cb) {
            int r = idx / Cb, c = idx % Cb;
            db[c * Rb + r] = f2bf(b[idx]);
        }
    }
}

// ---------------- per-row int8 quantization of w_hh ----------------
__global__ __launch_bounds__(64) void k_quant(const float* __restrict__ w, int* __restrict__ wq,
                                              float* __restrict__ wsc) {
    int row = blockIdx.x;   // 0..G3-1
    int t = threadIdx.x;    // 0..63
    const float* wr = w + (size_t)row * HID;
    float4 v = *(const float4*)(wr + t * 4);
    float m = fmaxf(fmaxf(fabsf(v.x), fabsf(v.y)), fmaxf(fabsf(v.z), fabsf(v.w)));
#pragma unroll
    for (int off = 1; off < 64; off <<= 1) m = fmaxf(m, __shfl_xor(m, off));
    float s = (m > 0.f) ? m * (1.0f / 127.0f) : 1.0f;
    float inv = 1.0f / s;
    int q0 = max(-127, min(127, __float2int_rn(v.x * inv)));
    int q1 = max(-127, min(127, __float2int_rn(v.y * inv)));
    int q2 = max(-127, min(127, __float2int_rn(v.z * inv)));
    int q3 = max(-127, min(127, __float2int_rn(v.w * inv)));
    wq[row * 64 + t] = (q0 & 0xFF) | ((q1 & 0xFF) << 8) | ((q2 & 0xFF) << 16) | ((q3 & 0xFF) << 24);
    if (t == 0) wsc[row] = s;
}

// ---------------- bf16 MFMA GEMM (R6-proven; used for prog/node) ----------------
__global__ __launch_bounds__(256) void k_mgemm(
    const float* __restrict__ A, const unsigned short* __restrict__ B16,
    float* __restrict__ out, const float* __restrict__ bias,
    const int* __restrict__ trace, const int* __restrict__ na,
    int mode, int M, int K, int N, int strideA, int ntiles, int brow0, int Bld, int dotanh)
{
    __shared__ short As[64][40];
    __shared__ short Bt[64][40];
    __shared__ int baseLds[64];
    __shared__ int validLds[64];
    int tid = threadIdx.x;
    int bm = blockIdx.x / ntiles, bn = blockIdx.x % ntiles;
    int m0 = bm * 64, n0 = bn * 64;
    if (tid < 64) {
        int m = m0 + tid;
        int valid = (m < M) ? 1 : 0;
        int base = 0;
        if (valid) {
            if (mode == 2) {
                int i = m >> 6, bb = m & 63;
                int node = trace[bb * TT + i];
                int asg = (node < NNODE) ? na[bb * NNODE + node] : 0;
                base = (node * DD + asg) * EE;
            } else {
                base = m * strideA;
            }
        }
        baseLds[tid] = base;
        validLds[tid] = valid;
    }
    __syncthreads();

    int wv = tid >> 6, l = tid & 63;
    int lr = l & 15, lg = l >> 4;
    f32x4 acc[4];
#pragma unroll
    for (int cb = 0; cb < 4; cb++) acc[cb] = (f32x4){0.f, 0.f, 0.f, 0.f};

    int ar = tid >> 2, aq = tid & 3;
    int bk = tid >> 3, bq = tid & 7;
    int nsteps = (K + 31) >> 5;
    for (int it = 0; it < nsteps; it++) {
        int kk = it * 32;
        {
            int base = baseLds[ar], val = validLds[ar];
            short8 t1;
#pragma unroll
            for (int j = 0; j < 8; j++) {
                int kx = kk + aq * 8 + j;
                float v = (val && kx < K) ? A[(size_t)base + kx] : 0.f;
                t1[j] = (short)f2bf(v);
            }
            *(short8*)&As[ar][aq * 8] = t1;
        }
        {
            int kx = kk + bk;
            short8 t2;
            if (kx < K) {
                t2 = *(const short8*)(B16 + (size_t)(brow0 + kx) * Bld + n0 + bq * 8);
            } else {
#pragma unroll
                for (int j = 0; j < 8; j++) t2[j] = 0;
            }
#pragma unroll
            for (int j = 0; j < 8; j++) Bt[bq * 8 + j][bk] = t2[j];
        }
        __syncthreads();
        short8 a = *(const short8*)&As[wv * 16 + lr][lg * 8];
#pragma unroll
        for (int cb = 0; cb < 4; cb++) {
            short8 bfr = *(const short8*)&Bt[cb * 16 + lr][lg * 8];
            acc[cb] = __builtin_amdgcn_mfma_f32_16x16x32_bf16(a, bfr, acc[cb], 0, 0, 0);
        }
        __syncthreads();
    }
#pragma unroll
    for (int cb = 0; cb < 4; cb++) {
        int col = n0 + cb * 16 + lr;
#pragma unroll
        for (int q = 0; q < 4; q++) {
            int row = m0 + wv * 16 + lg * 4 + q;
            if (row < M) {
                float v = acc[cb][q];
                if (bias) v += bias[col];
                if (dotanh) v = tanhf(v);
                out[(size_t)row * N + col] = v;
            }
        }
    }
}

// ---------------- label GEMM v2 (R15-proven): A cached once/block, fused addgi ----------------
#define LG_PITCH 328
__global__ __launch_bounds__(256) void k_lgemm2(
    const float* __restrict__ A, const unsigned short* __restrict__ B16,
    const float* __restrict__ node_t, const float* __restrict__ prog_t,
    const int* __restrict__ trace, const int* __restrict__ na,
    float* __restrict__ out)
{
    __shared__ short Afull[64][LG_PITCH];
    __shared__ short Bt[64][40];
    __shared__ int nodeLds[64];
    const int tid = threadIdx.x;
    const int ib = blockIdx.x >> 2;
    const int npg = blockIdx.x & 3;

    if (tid < 64) nodeLds[tid] = trace[tid * TT + ib];
    __syncthreads();

#pragma unroll
    for (int g = 0; g < 10; g++) {
        int idx = tid + g * 256;
        int row = idx / 40, c8 = idx % 40;
        int node = nodeLds[row];
        int asg = (node < NNODE) ? na[row * NNODE + node] : 0;
        const float* ap = A + (size_t)(node * DD + asg) * EE;
        short8 t1;
#pragma unroll
        for (int j = 0; j < 8; j++) {
            int kx = c8 * 8 + j;
            float v = (kx < EE) ? ap[kx] : 0.f;
            t1[j] = (short)f2bf(v);
        }
        *(short8*)&Afull[row][c8 * 8] = t1;
    }
    __syncthreads();

    const int wv = tid >> 6, l = tid & 63;
    const int lr = l & 15, lg = l >> 4;
    const int bk = tid >> 3, bq = tid & 7;

    for (int np = npg * 3; np < npg * 3 + 3; np++) {
        int n0 = np * 64;
        f32x4 acc[4];
#pragma unroll
        for (int cb = 0; cb < 4; cb++) acc[cb] = (f32x4){0.f, 0.f, 0.f, 0.f};
#pragma unroll
        for (int ks = 0; ks < 10; ks++) {
            int kx = ks * 32 + bk;
            short8 t2;
            if (kx < EE) {
                t2 = *(const short8*)(B16 + (size_t)kx * G3 + n0 + bq * 8);
            } else {
#pragma unroll
                for (int j = 0; j < 8; j++) t2[j] = 0;
            }
#pragma unroll
            for (int j = 0; j < 8; j++) Bt[bq * 8 + j][bk] = t2[j];
            __syncthreads();
            short8 a = *(const short8*)&Afull[wv * 16 + lr][ks * 32 + lg * 8];
#pragma unroll
            for (int cb = 0; cb < 4; cb++) {
                short8 bfr = *(const short8*)&Bt[cb * 16 + lr][lg * 8];
                acc[cb] = __builtin_amdgcn_mfma_f32_16x16x32_bf16(a, bfr, acc[cb], 0, 0, 0);
            }
            __syncthreads();
        }
#pragma unroll
        for (int cb = 0; cb < 4; cb++) {
            int col = n0 + cb * 16 + lr;
#pragma unroll
            for (int q = 0; q < 4; q++) {
                int rl = wv * 16 + lg * 4 + q;
                int node = nodeLds[rl];
                float v = acc[cb][q] + node_t[(size_t)node * G3 + col] + prog_t[(size_t)rl * G3 + col];
                out[((size_t)ib * 64 + rl) * G3 + col] = v;
            }
        }
    }
}

// ---------------- GRU recurrence: int8 weights, 1024 threads (16 waves -> 2x MLP) ----------------
// Thread (k = tid>>2, s = tid&3): quarter-K split (64 cols), shfl_xor(1)+(2) combine.
__global__ __launch_bounds__(1024) void rec11_kernel(
    const float* __restrict__ h0, const int* __restrict__ whh8q, const float* __restrict__ wsc,
    const float* __restrict__ bhh, const float* __restrict__ gsum, float* __restrict__ store)
{
    __shared__ float hs32[HID];
    __shared__ int hs8w[HID / 4];
    const int tid = threadIdx.x;
    const int s = tid & 3;
    const int k = tid >> 2;
    const int b = blockIdx.x;

    if (tid < HID) {
        float v = h0[(size_t)b * HID + tid];
        hs32[tid] = v;
        int q = max(-127, min(127, __float2int_rn(v * SCALE_H)));
        ((char*)hs8w)[tid] = (char)q;
    }

    int4 wR[4], wZ[4], wN[4];
    {
        const int4* pr = (const int4*)(whh8q + (size_t)k * 64 + s * 16);
        const int4* pz = (const int4*)(whh8q + (size_t)(HID + k) * 64 + s * 16);
        const int4* pn = (const int4*)(whh8q + (size_t)(2 * HID + k) * 64 + s * 16);
#pragma unroll
        for (int c8 = 0; c8 < 4; c8++) { wR[c8] = pr[c8]; wZ[c8] = pz[c8]; wN[c8] = pn[c8]; }
    }
    const float sR = wsc[k] * (1.0f / SCALE_H);
    const float sZ = wsc[HID + k] * (1.0f / SCALE_H);
    const float sN = wsc[2 * HID + k] * (1.0f / SCALE_H);
    const float bhr = bhh[k], bhz = bhh[HID + k], bhn = bhh[2 * HID + k];
    __syncthreads();

    float gr_c = 0.f, gz_c = 0.f, gn_c = 0.f;
    if (s == 0) {
        const float* lp = gsum + (size_t)b * G3;
        gr_c = lp[k]; gz_c = lp[HID + k]; gn_c = lp[2 * HID + k];
    }

    for (int i = 0; i < T1; i++) {
        float gr_n = 0.f, gz_n = 0.f, gn_n = 0.f;
        if (s == 0 && i + 1 < T1) {
            const float* lp = gsum + ((size_t)(i + 1) * BB + b) * G3;
            gr_n = lp[k]; gz_n = lp[HID + k]; gn_n = lp[2 * HID + k];
        }
        int ar = 0, az = 0, an = 0;
#pragma unroll
        for (int c8 = 0; c8 < 4; c8++) {
            int4 wr = wR[c8], wz = wZ[c8], wn = wN[c8];
            int hv0 = hs8w[s * 16 + c8 * 4 + 0];
            int hv1 = hs8w[s * 16 + c8 * 4 + 1];
            int hv2 = hs8w[s * 16 + c8 * 4 + 2];
            int hv3 = hs8w[s * 16 + c8 * 4 + 3];
            ar = dot4(wr.x, hv0, ar); az = dot4(wz.x, hv0, az); an = dot4(wn.x, hv0, an);
            ar = dot4(wr.y, hv1, ar); az = dot4(wz.y, hv1, az); an = dot4(wn.y, hv1, an);
            ar = dot4(wr.z, hv2, ar); az = dot4(wz.z, hv2, az); an = dot4(wn.z, hv2, an);
            ar = dot4(wr.w, hv3, ar); az = dot4(wz.w, hv3, az); an = dot4(wn.w, hv3, an);
        }
        ar += __shfl_xor(ar, 1); az += __shfl_xor(az, 1); an += __shfl_xor(an, 1);
        ar += __shfl_xor(ar, 2); az += __shfl_xor(az, 2); an += __shfl_xor(an, 2);
        __syncthreads();   // all reads of hs8w done
        if (s == 0) {
            float arf = (float)ar * sR, azf = (float)az * sZ, anf = (float)an * sN;
            float r = 1.f / (1.f + expf(-(gr_c + arf + bhr)));
            float z = 1.f / (1.f + expf(-(gz_c + azf + bhz)));
            float n = tanhf(gn_c + r * (anf + bhn));
            float hold = hs32[k];
            float hnew = (1.f - z) * n + z * hold;
            hs32[k] = hnew;
            store[((size_t)b * T1 + i) * HID + k] = hnew;
            int q = max(-127, min(127, __float2int_rn(hnew * SCALE_H)));
            ((char*)hs8w)[k] = (char)q;
        }
        __syncthreads();   // writes visible for next step
        gr_c = gr_n; gz_c = gz_n; gn_c = gn_n;
    }
}

// ---------------- fused U = tanh(store @ ws1^T) + scores = U @ ws2^T ----------------
// 127 blocks x 256 thr. Block owns 64 store rows; A and U tiles live in LDS; Ubuf never materialized.
#define US_PITCH 264
__global__ __launch_bounds__(256) void k_uscore(
    const float* __restrict__ store, const unsigned short* __restrict__ ws1T16,
    const float* __restrict__ ws2, float* __restrict__ sbuf)
{
    __shared__ short As[64][US_PITCH];   // 33,792 B
    __shared__ short Ub[64][US_PITCH];   // 33,792 B
    __shared__ short Bt[64][40];         //  5,120 B
    const int tid = threadIdx.x;
    const int m0 = blockIdx.x * 64;

    // stage A: 64 rows x 256 k, f32 -> bf16
#pragma unroll
    for (int g = 0; g < 8; g++) {
        int idx = tid + g * 256;          // 0..2047
        int row = idx >> 5, c8 = idx & 31;
        const float* ap = store + (size_t)(m0 + row) * HID + c8 * 8;
        short8 t1;
#pragma unroll
        for (int j = 0; j < 8; j++) t1[j] = (short)f2bf(ap[j]);
        *(short8*)&As[row][c8 * 8] = t1;
    }
    __syncthreads();

    const int wv = tid >> 6, l = tid & 63;
    const int lr = l & 15, lg = l >> 4;
    const int bk = tid >> 3, bq = tid & 7;

    for (int np = 0; np < 4; np++) {
        int n0 = np * 64;
        f32x4 acc[4];
#pragma unroll
        for (int cb = 0; cb < 4; cb++) acc[cb] = (f32x4){0.f, 0.f, 0.f, 0.f};
#pragma unroll
        for (int ks = 0; ks < 8; ks++) {
            int kx = ks * 32 + bk;
            short8 t2 = *(const short8*)(ws1T16 + (size_t)kx * HID + n0 + bq * 8);
#pragma unroll
            for (int j = 0; j < 8; j++) Bt[bq * 8 + j][bk] = t2[j];
            __syncthreads();
            short8 a = *(const short8*)&As[wv * 16 + lr][ks * 32 + lg * 8];
#pragma unroll
            for (int cb = 0; cb < 4; cb++) {
                short8 bfr = *(const short8*)&Bt[cb * 16 + lr][lg * 8];
                acc[cb] = __builtin_amdgcn_mfma_f32_16x16x32_bf16(a, bfr, acc[cb], 0, 0, 0);
            }
            __syncthreads();
        }
#pragma unroll
        for (int cb = 0; cb < 4; cb++) {
            int col = n0 + cb * 16 + lr;
#pragma unroll
            for (int q = 0; q < 4; q++) {
                int row = wv * 16 + lg * 4 + q;
                Ub[row][col] = (short)f2bf(tanhf(acc[cb][q]));
            }
        }
    }
    __syncthreads();   // Ub complete

    // scores: 64 rows x 5 heads = 320 dots over 256
    for (int d = tid; d < 64 * NHEADS; d += 256) {
        int row = d / NHEADS, h = d % NHEADS;
        const float* w2 = ws2 + h * HID;
        float acc = 0.f;
#pragma unroll 4
        for (int c = 0; c < HID; c += 8) {
            short8 u8 = *(const short8*)&Ub[row][c];
#pragma unroll
            for (int j = 0; j < 8; j++)
                acc += bf2f((unsigned short)u8[j]) * w2[c + j];
        }
        sbuf[(size_t)(m0 + row) * NHEADS + h] = acc;
    }
}

// ---------------- parallel per-(b,h) softmax: max-reduce + prefix scan ----------------
__global__ __launch_bounds__(128) void k_softmax_par(const float* __restrict__ sbuf,
                                                     float* __restrict__ ebuf, float* __restrict__ rD) {
    __shared__ float a[128];
    int bh = blockIdx.x;
    int b = bh / NHEADS, h = bh % NHEADS;
    int t = threadIdx.x;
    const float* sp = sbuf + (size_t)b * T1 * NHEADS + h;
    float sv = (t < T1) ? sp[t * NHEADS] : -1e30f;
    a[t] = sv;
    __syncthreads();
#pragma unroll
    for (int off = 64; off >= 1; off >>= 1) {
        if (t < off) a[t] = fmaxf(a[t], a[t + off]);
        __syncthreads();
    }
    float m = a[0];
    __syncthreads();
    float e = (t < T1) ? expf(sv - m) : 0.f;
    a[t] = e;
#pragma unroll
    for (int off = 1; off < 128; off <<= 1) {
        __syncthreads();
        float v = (t >= off) ? a[t - off] : 0.f;
        __syncthreads();
        a[t] += v;
    }
    if (t < T1) {
        ebuf[(b * T1 + t) * NHEADS + h] = e;
        rD[(b * T1 + t) * NHEADS + h] = 1.f / a[t];
    }
}

// ---------------- alphas output ----------------
__global__ void k_alphas(const float* __restrict__ ebuf, const float* __restrict__ rD, float* __restrict__ alph) {
    int flat = blockIdx.x * 256 + threadIdx.x;
    const int TOT = T1 * BB * T1 * NHEADS;
    if (flat < TOT) {
        int i = flat / (BB * T1 * NHEADS);
        int rem = flat % (BB * T1 * NHEADS);
        int b = rem / (T1 * NHEADS);
        int rem2 = rem % (T1 * NHEADS);
        int t = rem2 / NHEADS, h = rem2 % NHEADS;
        float v = 0.f;
        if (t <= i) v = ebuf[(b * T1 + t) * NHEADS + h] * rD[(b * T1 + i) * NHEADS + h];
        alph[flat] = v;
    }
}

// ---------------- ctx prefix scan -> bf16 output ----------------
__global__ __launch_bounds__(256) void k_ctx(const float* __restrict__ ebuf, const float* __restrict__ rD,
                                             const float* __restrict__ store, unsigned short* __restrict__ ctx16) {
    __shared__ float eL[T1], rL[T1];
    int b = blockIdx.x / NHEADS, h = blockIdx.x % NHEADS;
    int k = threadIdx.x;
    if (k < T1) {
        eL[k] = ebuf[(b * T1 + k) * NHEADS + h];
        rL[k] = rD[(b * T1 + k) * NHEADS + h];
    }
    __syncthreads();
    float acc = 0.f;
#pragma unroll 4
    for (int t = 0; t < T1; t++) {
        acc += eL[t] * store[((size_t)b * T1 + t) * HID + k];
        ctx16[((size_t)t * BB + b) * ATT + h * HID + k] = f2bf(acc * rL[t]);
    }
}

// ---------------- fused single-block expert bucketing ----------------
__global__ __launch_bounds__(1024) void k_bucket(const int* __restrict__ trace,
                                                 int* __restrict__ boff, int* __restrict__ items) {
    __shared__ int cnt[NNODE + 1];
    __shared__ int cur[NNODE + 1];
    __shared__ int part[256];
    int t = threadIdx.x;
    for (int x = t; x < NNODE + 1; x += 1024) cnt[x] = 0;
    __syncthreads();
    for (int idx = t; idx < T1 * BB; idx += 1024) {
        int i = idx >> 6, b = idx & 63;
        int node = trace[b * TT + i + 1];
        atomicAdd(&cnt[node], 1);
    }
    __syncthreads();
    int s0 = 0;
    if (t < 256) {
#pragma unroll
        for (int j = 0; j < 8; j++) { int idx = t * 8 + j; if (idx < NNODE + 1) s0 += cnt[idx]; }
        part[t] = s0;
    }
    __syncthreads();
    for (int off = 1; off < 256; off <<= 1) {
        int u = 0;
        if (t < 256 && t >= off) u = part[t - off];
        __syncthreads();
        if (t < 256) part[t] += u;
        __syncthreads();
    }
    if (t < 256) {
        int run = part[t] - s0;
        for (int j = 0; j < 8; j++) {
            int idx = t * 8 + j;
            if (idx < NNODE + 1) { boff[idx] = run; cur[idx] = run; run += cnt[idx]; }
        }
        if (t == 255) boff[NNODE + 1] = part[255];
    }
    __syncthreads();
    for (int idx = t; idx < T1 * BB; idx += 1024) {
        int i = idx >> 6, b = idx & 63;
        int node = trace[b * TT + i + 1];
        int pos = atomicAdd(&cur[node], 1);
        items[pos] = idx;
    }
}

// one block per expert: stream weights once for all its items (chunks of 8); ctx in bf16
__global__ __launch_bounds__(256) void k_pred2(
    const unsigned short* __restrict__ ctx16, const float* __restrict__ pw, const float* __restrict__ pb,
    const int* __restrict__ boff, const int* __restrict__ items, float* __restrict__ outs)
{
    __shared__ float cl[8][ATT];
    __shared__ float red[16][16][8];
    int e = blockIdx.x;
    int start = boff[e], end = boff[e + 1];
    if (start == end) return;
    int tid = threadIdx.x;
    int d = tid & 15, ks = tid >> 4;
    const float* w = pw + (size_t)e * ATT * DD;
    float biasv = pb[e * DD + d];
    for (int c0 = start; c0 < end; c0 += 8) {
        int cn = min(8, end - c0);
        for (int j = 0; j < cn; j++) {
            int item = items[c0 + j];
            const unsigned short* cp = ctx16 + (size_t)item * ATT;
            for (int x = tid; x < ATT; x += 256)
                cl[j][x] = bf2f(cp[x]);
        }
        __syncthreads();
        float acc[8];
#pragma unroll
        for (int j = 0; j < 8; j++) acc[j] = 0.f;
        for (int kx = ks * 80; kx < ks * 80 + 80; kx++) {
            float wv = w[kx * DD + d];
#pragma unroll
            for (int j = 0; j < 8; j++) acc[j] += cl[j][kx] * wv;
        }
#pragma unroll
        for (int j = 0; j < 8; j++) red[ks][d][j] = acc[j];
        __syncthreads();
#pragma unroll
        for (int st = 8; st >= 1; st >>= 1) {
            if (ks < st) {
#pragma unroll
                for (int j = 0; j < 8; j++) red[ks][d][j] += red[ks + st][d][j];
            }
            __syncthreads();
        }
        if (ks == 0) {
            for (int j = 0; j < cn; j++) {
                int item = items[c0 + j];
                outs[(size_t)item * DD + d] = red[0][d][j] + biasv;
            }
        }
        __syncthreads();
    }
}

extern "C" void kernel_launch(void* const* d_in, const int* in_sizes, int n_in,
                              void* d_out, int out_size, void* d_ws, size_t ws_size,
                              hipStream_t stream) {
    const float* program_emb = (const float*)d_in[0];
    const float* h0       = (const float*)d_in[1];
    const float* node_emb = (const float*)d_in[2];
    const float* label_emb= (const float*)d_in[3];
    const float* w_ih     = (const float*)d_in[4];
    const float* w_hh     = (const float*)d_in[5];
    const float* b_ih     = (const float*)d_in[6];
    const float* b_hh     = (const float*)d_in[7];
    const float* ws1      = (const float*)d_in[8];
    const float* ws2      = (const float*)d_in[9];
    const float* pred_w   = (const float*)d_in[10];
    const float* pred_b   = (const float*)d_in[11];
    const int*   trace    = (const int*)d_in[12];
    const int*   na       = (const int*)d_in[13];

    // ---- R9/R12-proven layout (floats), UNCHANGED ----
    float*          ws      = (float*)d_ws;
    float*          store   = ws + 0;           // [0 .. 2,080,768)
    unsigned short* wihT16  = (unsigned short*)(ws + 2080768);   // dead after lgemm2
    unsigned short* ws1T16  = (unsigned short*)(ws + 2409472);   // dead after uscore
    float*          prog_t  = ws + 2803712;
    float*          node_t  = ws + 2852864;
    float*          sbuf    = ws + 4389632;
    float*          ebuf    = ws + 4430272;
    float*          rD      = ws + 4470912;
    float*          label_p = ws + 4511568;     // gsum (fused add); dead after rec11
    int*            whh8q   = (int*)(ws + 12834640);   // dead after rec11
    float*          wsc     = ws + 12883792;           // dead after rec11
    unsigned short* ctx16   = (unsigned short*)(ws + 4511568);   // aliases label_p (post-rec)
    int*            cnt_    = (int*)(ws + 2080768);    // over dead wihT16 (post-lgemm2)
    int*            boff    = cnt_ + 4096;
    int*            items   = boff + 2048;

    float* outs = (float*)d_out;
    float* alph = outs + T1 * BB * DD;

    // P1: static precompute
    k_tcvt2<<<2824, 256, 0, stream>>>(w_ih, wihT16, G3, 856, ws1, ws1T16, HID, HID);
    k_quant<<<G3, 64, 0, stream>>>(w_hh, whh8q, wsc);
    k_mgemm<<<12,   256, 0, stream>>>(program_emb, wihT16, prog_t, b_ih,   nullptr, nullptr, 0, 64,   256, G3,  256, 12, 300, G3, 0);
    k_mgemm<<<384,  256, 0, stream>>>(node_emb,    wihT16, node_t, nullptr, nullptr, nullptr, 0, 2001, 300, G3,  300, 12, 556, G3, 0);
    k_lgemm2<<<508, 256, 0, stream>>>(label_emb, wihT16, node_t, prog_t, trace, na, label_p);

    // P2: sequential recurrence — int8 weights, 1024-thread blocks (2x MLP)
    rec11_kernel<<<64, 1024, 0, stream>>>(h0, whh8q, wsc, b_hh, label_p, store);

    // P3: parallel attention + prediction
    k_uscore<<<127, 256, 0, stream>>>(store, ws1T16, ws2, sbuf);
    k_softmax_par<<<BB * NHEADS, 128, 0, stream>>>(sbuf, ebuf, rD);
    k_alphas<<<20162, 256, 0, stream>>>(ebuf, rD, alph);
    k_ctx<<<320, 256, 0, stream>>>(ebuf, rD, store, ctx16);

    // fused expert bucketing + prediction
    k_bucket<<<1, 1024, 0, stream>>>(trace, boff, items);
    k_pred2<<<NNODE + 1, 256, 0, stream>>>(ctx16, pred_w, pred_b, boff, items, outs);
}

// Round 18
// 366.544 us; speedup vs baseline: 1.1002x; 1.1002x over previous
//
#include <hip/hip_runtime.h>
#include <hip/hip_bf16.h>
#include <math.h>

#define BB 64
#define TT 128
#define T1 127
#define NNODE 2000
#define EE 300
#define HID 256
#define NHEADS 5
#define DD 16
#define G3 768
#define ATT 1280
#define SCALE_H 28.0f

typedef _Float16 h2_t __attribute__((ext_vector_type(2)));
typedef short short8 __attribute__((ext_vector_type(8)));
typedef float f32x4 __attribute__((ext_vector_type(4)));

__device__ __forceinline__ int dot4(int a, int b, int c) {
#if __has_builtin(__builtin_amdgcn_sdot4)
    return __builtin_amdgcn_sdot4(a, b, c, false);
#else
    int r;
    asm("v_dot4_i32_i8 %0, %1, %2, %3" : "=v"(r) : "v"(a), "v"(b), "v"(c));
    return r;
#endif
}

__device__ __forceinline__ unsigned short f2bf(float f) {
    unsigned u = __float_as_uint(f);
    unsigned r = (u + 0x7FFFu + ((u >> 16) & 1u)) >> 16;   // RNE
    return (unsigned short)r;
}

__device__ __forceinline__ float bf2f(unsigned short u) {
    return __uint_as_float((unsigned)u << 16);
}

// ---------------- merged prep: transpose-cvt w_ih + ws1, and int8-quant w_hh ----------------
// blocks [0, 2824): tcvt of w_ih then ws1. blocks [2824, 3016): quant, 4 rows/block.
__global__ __launch_bounds__(256) void k_prep(
    const float* __restrict__ wih, unsigned short* __restrict__ wihT,
    const float* __restrict__ ws1, unsigned short* __restrict__ ws1T,
    const float* __restrict__ whh, int* __restrict__ wq, float* __restrict__ wsc)
{
    int bid = blockIdx.x;
    int tid = threadIdx.x;
    if (bid < 2824) {
        int idx = bid * 256 + tid;
        int na = G3 * 856;
        if (idx < na) {
            int r = idx / 856, c = idx % 856;
            wihT[c * G3 + r] = f2bf(wih[idx]);
        } else {
            idx -= na;
            if (idx < HID * HID) {
                int r = idx / HID, c = idx % HID;
                ws1T[c * HID + r] = f2bf(ws1[idx]);
            }
        }
    } else {
        int row = (bid - 2824) * 4 + (tid >> 6);   // 4 rows/block, 64 lanes each
        int t = tid & 63;
        if (row < G3) {
            const float* wr = whh + (size_t)row * HID;
            float4 v = *(const float4*)(wr + t * 4);
            float m = fmaxf(fmaxf(fabsf(v.x), fabsf(v.y)), fmaxf(fabsf(v.z), fabsf(v.w)));
#pragma unroll
            for (int off = 1; off < 64; off <<= 1) m = fmaxf(m, __shfl_xor(m, off));
            float s = (m > 0.f) ? m * (1.0f / 127.0f) : 1.0f;
            float inv = 1.0f / s;
            int q0 = max(-127, min(127, __float2int_rn(v.x * inv)));
            int q1 = max(-127, min(127, __float2int_rn(v.y * inv)));
            int q2 = max(-127, min(127, __float2int_rn(v.z * inv)));
            int q3 = max(-127, min(127, __float2int_rn(v.w * inv)));
            wq[row * 64 + t] = (q0 & 0xFF) | ((q1 & 0xFF) << 8) | ((q2 & 0xFF) << 16) | ((q3 & 0xFF) << 24);
            if (t == 0) wsc[row] = s;
        }
    }
}

// ---------------- bf16 MFMA GEMM (R6-proven; used for prog/node) ----------------
__global__ __launch_bounds__(256) void k_mgemm(
    const float* __restrict__ A, const unsigned short* __restrict__ B16,
    float* __restrict__ out, const float* __restrict__ bias,
    const int* __restrict__ trace, const int* __restrict__ na,
    int mode, int M, int K, int N, int strideA, int ntiles, int brow0, int Bld, int dotanh)
{
    __shared__ short As[64][40];
    __shared__ short Bt[64][40];
    __shared__ int baseLds[64];
    __shared__ int validLds[64];
    int tid = threadIdx.x;
    int bm = blockIdx.x / ntiles, bn = blockIdx.x % ntiles;
    int m0 = bm * 64, n0 = bn * 64;
    if (tid < 64) {
        int m = m0 + tid;
        int valid = (m < M) ? 1 : 0;
        int base = 0;
        if (valid) {
            if (mode == 2) {
                int i = m >> 6, bb = m & 63;
                int node = trace[bb * TT + i];
                int asg = (node < NNODE) ? na[bb * NNODE + node] : 0;
                base = (node * DD + asg) * EE;
            } else {
                base = m * strideA;
            }
        }
        baseLds[tid] = base;
        validLds[tid] = valid;
    }
    __syncthreads();

    int wv = tid >> 6, l = tid & 63;
    int lr = l & 15, lg = l >> 4;
    f32x4 acc[4];
#pragma unroll
    for (int cb = 0; cb < 4; cb++) acc[cb] = (f32x4){0.f, 0.f, 0.f, 0.f};

    int ar = tid >> 2, aq = tid & 3;
    int bk = tid >> 3, bq = tid & 7;
    int nsteps = (K + 31) >> 5;
    for (int it = 0; it < nsteps; it++) {
        int kk = it * 32;
        {
            int base = baseLds[ar], val = validLds[ar];
            short8 t1;
#pragma unroll
            for (int j = 0; j < 8; j++) {
                int kx = kk + aq * 8 + j;
                float v = (val && kx < K) ? A[(size_t)base + kx] : 0.f;
                t1[j] = (short)f2bf(v);
            }
            *(short8*)&As[ar][aq * 8] = t1;
        }
        {
            int kx = kk + bk;
            short8 t2;
            if (kx < K) {
                t2 = *(const short8*)(B16 + (size_t)(brow0 + kx) * Bld + n0 + bq * 8);
            } else {
#pragma unroll
                for (int j = 0; j < 8; j++) t2[j] = 0;
            }
#pragma unroll
            for (int j = 0; j < 8; j++) Bt[bq * 8 + j][bk] = t2[j];
        }
        __syncthreads();
        short8 a = *(const short8*)&As[wv * 16 + lr][lg * 8];
#pragma unroll
        for (int cb = 0; cb < 4; cb++) {
            short8 bfr = *(const short8*)&Bt[cb * 16 + lr][lg * 8];
            acc[cb] = __builtin_amdgcn_mfma_f32_16x16x32_bf16(a, bfr, acc[cb], 0, 0, 0);
        }
        __syncthreads();
    }
#pragma unroll
    for (int cb = 0; cb < 4; cb++) {
        int col = n0 + cb * 16 + lr;
#pragma unroll
        for (int q = 0; q < 4; q++) {
            int row = m0 + wv * 16 + lg * 4 + q;
            if (row < M) {
                float v = acc[cb][q];
                if (bias) v += bias[col];
                if (dotanh) v = tanhf(v);
                out[(size_t)row * N + col] = v;
            }
        }
    }
}

// ---------------- label GEMM v2 (R15-proven): A cached once/block, fused addgi ----------------
#define LG_PITCH 328
__global__ __launch_bounds__(256) void k_lgemm2(
    const float* __restrict__ A, const unsigned short* __restrict__ B16,
    const float* __restrict__ node_t, const float* __restrict__ prog_t,
    const int* __restrict__ trace, const int* __restrict__ na,
    float* __restrict__ out)
{
    __shared__ short Afull[64][LG_PITCH];
    __shared__ short Bt[64][40];
    __shared__ int nodeLds[64];
    const int tid = threadIdx.x;
    const int ib = blockIdx.x >> 2;
    const int npg = blockIdx.x & 3;

    if (tid < 64) nodeLds[tid] = trace[tid * TT + ib];
    __syncthreads();

#pragma unroll
    for (int g = 0; g < 10; g++) {
        int idx = tid + g * 256;
        int row = idx / 40, c8 = idx % 40;
        int node = nodeLds[row];
        int asg = (node < NNODE) ? na[row * NNODE + node] : 0;
        const float* ap = A + (size_t)(node * DD + asg) * EE;
        short8 t1;
#pragma unroll
        for (int j = 0; j < 8; j++) {
            int kx = c8 * 8 + j;
            float v = (kx < EE) ? ap[kx] : 0.f;
            t1[j] = (short)f2bf(v);
        }
        *(short8*)&Afull[row][c8 * 8] = t1;
    }
    __syncthreads();

    const int wv = tid >> 6, l = tid & 63;
    const int lr = l & 15, lg = l >> 4;
    const int bk = tid >> 3, bq = tid & 7;

    for (int np = npg * 3; np < npg * 3 + 3; np++) {
        int n0 = np * 64;
        f32x4 acc[4];
#pragma unroll
        for (int cb = 0; cb < 4; cb++) acc[cb] = (f32x4){0.f, 0.f, 0.f, 0.f};
#pragma unroll
        for (int ks = 0; ks < 10; ks++) {
            int kx = ks * 32 + bk;
            short8 t2;
            if (kx < EE) {
                t2 = *(const short8*)(B16 + (size_t)kx * G3 + n0 + bq * 8);
            } else {
#pragma unroll
                for (int j = 0; j < 8; j++) t2[j] = 0;
            }
#pragma unroll
            for (int j = 0; j < 8; j++) Bt[bq * 8 + j][bk] = t2[j];
            __syncthreads();
            short8 a = *(const short8*)&Afull[wv * 16 + lr][ks * 32 + lg * 8];
#pragma unroll
            for (int cb = 0; cb < 4; cb++) {
                short8 bfr = *(const short8*)&Bt[cb * 16 + lr][lg * 8];
                acc[cb] = __builtin_amdgcn_mfma_f32_16x16x32_bf16(a, bfr, acc[cb], 0, 0, 0);
            }
            __syncthreads();
        }
#pragma unroll
        for (int cb = 0; cb < 4; cb++) {
            int col = n0 + cb * 16 + lr;
#pragma unroll
            for (int q = 0; q < 4; q++) {
                int rl = wv * 16 + lg * 4 + q;
                int node = nodeLds[rl];
                float v = acc[cb][q] + node_t[(size_t)node * G3 + col] + prog_t[(size_t)rl * G3 + col];
                out[((size_t)ib * 64 + rl) * G3 + col] = v;
            }
        }
    }
}

// ---------------- GRU recurrence: int8 weights, 512 thr (R15/R16-proven 125 us) ----------------
__global__ __launch_bounds__(512, 2) void rec10_kernel(
    const float* __restrict__ h0, const int* __restrict__ whh8q, const float* __restrict__ wsc,
    const float* __restrict__ bhh, const float* __restrict__ gsum, float* __restrict__ store)
{
    __shared__ float hs32[HID];
    __shared__ int hs8w[HID / 4];
    const int tid = threadIdx.x;
    const int s = tid & 1;
    const int k = tid >> 1;
    const int b = blockIdx.x;

    if (tid < HID) {
        float v = h0[(size_t)b * HID + tid];
        hs32[tid] = v;
        int q = max(-127, min(127, __float2int_rn(v * SCALE_H)));
        ((char*)hs8w)[tid] = (char)q;
    }

    int4 wR[8], wZ[8], wN[8];
    {
        const int4* pr = (const int4*)(whh8q + (size_t)k * 64 + s * 32);
        const int4* pz = (const int4*)(whh8q + (size_t)(HID + k) * 64 + s * 32);
        const int4* pn = (const int4*)(whh8q + (size_t)(2 * HID + k) * 64 + s * 32);
#pragma unroll
        for (int c8 = 0; c8 < 8; c8++) { wR[c8] = pr[c8]; wZ[c8] = pz[c8]; wN[c8] = pn[c8]; }
    }
    const float sR = wsc[k] * (1.0f / SCALE_H);
    const float sZ = wsc[HID + k] * (1.0f / SCALE_H);
    const float sN = wsc[2 * HID + k] * (1.0f / SCALE_H);
    const float bhr = bhh[k], bhz = bhh[HID + k], bhn = bhh[2 * HID + k];
    __syncthreads();

    float gr_c = 0.f, gz_c = 0.f, gn_c = 0.f;
    if (s == 0) {
        const float* lp = gsum + (size_t)b * G3;
        gr_c = lp[k]; gz_c = lp[HID + k]; gn_c = lp[2 * HID + k];
    }

    for (int i = 0; i < T1; i++) {
        float gr_n = 0.f, gz_n = 0.f, gn_n = 0.f;
        if (s == 0 && i + 1 < T1) {
            const float* lp = gsum + ((size_t)(i + 1) * BB + b) * G3;
            gr_n = lp[k]; gz_n = lp[HID + k]; gn_n = lp[2 * HID + k];
        }
        int ar = 0, az = 0, an = 0;
#pragma unroll
        for (int c8 = 0; c8 < 8; c8++) {
            int4 wr = wR[c8], wz = wZ[c8], wn = wN[c8];
            int hv0 = hs8w[s * 32 + c8 * 4 + 0];
            int hv1 = hs8w[s * 32 + c8 * 4 + 1];
            int hv2 = hs8w[s * 32 + c8 * 4 + 2];
            int hv3 = hs8w[s * 32 + c8 * 4 + 3];
            ar = dot4(wr.x, hv0, ar); az = dot4(wz.x, hv0, az); an = dot4(wn.x, hv0, an);
            ar = dot4(wr.y, hv1, ar); az = dot4(wz.y, hv1, az); an = dot4(wn.y, hv1, an);
            ar = dot4(wr.z, hv2, ar); az = dot4(wz.z, hv2, az); an = dot4(wn.z, hv2, an);
            ar = dot4(wr.w, hv3, ar); az = dot4(wz.w, hv3, az); an = dot4(wn.w, hv3, an);
        }
        ar += __shfl_xor(ar, 1); az += __shfl_xor(az, 1); an += __shfl_xor(an, 1);
        __syncthreads();   // all reads of hs8w done
        if (s == 0) {
            float arf = (float)ar * sR, azf = (float)az * sZ, anf = (float)an * sN;
            float r = 1.f / (1.f + expf(-(gr_c + arf + bhr)));
            float z = 1.f / (1.f + expf(-(gz_c + azf + bhz)));
            float n = tanhf(gn_c + r * (anf + bhn));
            float hold = hs32[k];
            float hnew = (1.f - z) * n + z * hold;
            hs32[k] = hnew;
            store[((size_t)b * T1 + i) * HID + k] = hnew;
            int q = max(-127, min(127, __float2int_rn(hnew * SCALE_H)));
            ((char*)hs8w)[k] = (char)q;
        }
        __syncthreads();   // writes visible for next step
        gr_c = gr_n; gz_c = gz_n; gn_c = gn_n;
    }
}

// ---------------- fused U = tanh(store @ ws1^T) + scores = U @ ws2^T (R17-proven) ----------------
#define US_PITCH 264
__global__ __launch_bounds__(256) void k_uscore(
    const float* __restrict__ store, const unsigned short* __restrict__ ws1T16,
    const float* __restrict__ ws2, float* __restrict__ sbuf)
{
    __shared__ short As[64][US_PITCH];
    __shared__ short Ub[64][US_PITCH];
    __shared__ short Bt[64][40];
    const int tid = threadIdx.x;
    const int m0 = blockIdx.x * 64;

#pragma unroll
    for (int g = 0; g < 8; g++) {
        int idx = tid + g * 256;
        int row = idx >> 5, c8 = idx & 31;
        const float* ap = store + (size_t)(m0 + row) * HID + c8 * 8;
        short8 t1;
#pragma unroll
        for (int j = 0; j < 8; j++) t1[j] = (short)f2bf(ap[j]);
        *(short8*)&As[row][c8 * 8] = t1;
    }
    __syncthreads();

    const int wv = tid >> 6, l = tid & 63;
    const int lr = l & 15, lg = l >> 4;
    const int bk = tid >> 3, bq = tid & 7;

    for (int np = 0; np < 4; np++) {
        int n0 = np * 64;
        f32x4 acc[4];
#pragma unroll
        for (int cb = 0; cb < 4; cb++) acc[cb] = (f32x4){0.f, 0.f, 0.f, 0.f};
#pragma unroll
        for (int ks = 0; ks < 8; ks++) {
            int kx = ks * 32 + bk;
            short8 t2 = *(const short8*)(ws1T16 + (size_t)kx * HID + n0 + bq * 8);
#pragma unroll
            for (int j = 0; j < 8; j++) Bt[bq * 8 + j][bk] = t2[j];
            __syncthreads();
            short8 a = *(const short8*)&As[wv * 16 + lr][ks * 32 + lg * 8];
#pragma unroll
            for (int cb = 0; cb < 4; cb++) {
                short8 bfr = *(const short8*)&Bt[cb * 16 + lr][lg * 8];
                acc[cb] = __builtin_amdgcn_mfma_f32_16x16x32_bf16(a, bfr, acc[cb], 0, 0, 0);
            }
            __syncthreads();
        }
#pragma unroll
        for (int cb = 0; cb < 4; cb++) {
            int col = n0 + cb * 16 + lr;
#pragma unroll
            for (int q = 0; q < 4; q++) {
                int row = wv * 16 + lg * 4 + q;
                Ub[row][col] = (short)f2bf(tanhf(acc[cb][q]));
            }
        }
    }
    __syncthreads();

    for (int d = tid; d < 64 * NHEADS; d += 256) {
        int row = d / NHEADS, h = d % NHEADS;
        const float* w2 = ws2 + h * HID;
        float acc = 0.f;
#pragma unroll 4
        for (int c = 0; c < HID; c += 8) {
            short8 u8 = *(const short8*)&Ub[row][c];
#pragma unroll
            for (int j = 0; j < 8; j++)
                acc += bf2f((unsigned short)u8[j]) * w2[c + j];
        }
        sbuf[(size_t)(m0 + row) * NHEADS + h] = acc;
    }
}

// ---------------- parallel per-(b,h) softmax: max-reduce + prefix scan ----------------
__global__ __launch_bounds__(128) void k_softmax_par(const float* __restrict__ sbuf,
                                                     float* __restrict__ ebuf, float* __restrict__ rD) {
    __shared__ float a[128];
    int bh = blockIdx.x;
    int b = bh / NHEADS, h = bh % NHEADS;
    int t = threadIdx.x;
    const float* sp = sbuf + (size_t)b * T1 * NHEADS + h;
    float sv = (t < T1) ? sp[t * NHEADS] : -1e30f;
    a[t] = sv;
    __syncthreads();
#pragma unroll
    for (int off = 64; off >= 1; off >>= 1) {
        if (t < off) a[t] = fmaxf(a[t], a[t + off]);
        __syncthreads();
    }
    float m = a[0];
    __syncthreads();
    float e = (t < T1) ? expf(sv - m) : 0.f;
    a[t] = e;
#pragma unroll
    for (int off = 1; off < 128; off <<= 1) {
        __syncthreads();
        float v = (t >= off) ? a[t - off] : 0.f;
        __syncthreads();
        a[t] += v;
    }
    if (t < T1) {
        ebuf[(b * T1 + t) * NHEADS + h] = e;
        rD[(b * T1 + t) * NHEADS + h] = 1.f / a[t];
    }
}

// ---------------- alphas output ----------------
__global__ void k_alphas(const float* __restrict__ ebuf, const float* __restrict__ rD, float* __restrict__ alph) {
    int flat = blockIdx.x * 256 + threadIdx.x;
    const int TOT = T1 * BB * T1 * NHEADS;
    if (flat < TOT) {
        int i = flat / (BB * T1 * NHEADS);
        int rem = flat % (BB * T1 * NHEADS);
        int b = rem / (T1 * NHEADS);
        int rem2 = rem % (T1 * NHEADS);
        int t = rem2 / NHEADS, h = rem2 % NHEADS;
        float v = 0.f;
        if (t <= i) v = ebuf[(b * T1 + t) * NHEADS + h] * rD[(b * T1 + i) * NHEADS + h];
        alph[flat] = v;
    }
}

// ---------------- ctx prefix scan -> bf16 output ----------------
__global__ __launch_bounds__(256) void k_ctx(const float* __restrict__ ebuf, const float* __restrict__ rD,
                                             const float* __restrict__ store, unsigned short* __restrict__ ctx16) {
    __shared__ float eL[T1], rL[T1];
    int b = blockIdx.x / NHEADS, h = blockIdx.x % NHEADS;
    int k = threadIdx.x;
    if (k < T1) {
        eL[k] = ebuf[(b * T1 + k) * NHEADS + h];
        rL[k] = rD[(b * T1 + k) * NHEADS + h];
    }
    __syncthreads();
    float acc = 0.f;
#pragma unroll 4
    for (int t = 0; t < T1; t++) {
        acc += eL[t] * store[((size_t)b * T1 + t) * HID + k];
        ctx16[((size_t)t * BB + b) * ATT + h * HID + k] = f2bf(acc * rL[t]);
    }
}

// ---------------- fused single-block expert bucketing ----------------
__global__ __launch_bounds__(1024) void k_bucket(const int* __restrict__ trace,
                                                 int* __restrict__ boff, int* __restrict__ items) {
    __shared__ int cnt[NNODE + 1];
    __shared__ int cur[NNODE + 1];
    __shared__ int part[256];
    int t = threadIdx.x;
    for (int x = t; x < NNODE + 1; x += 1024) cnt[x] = 0;
    __syncthreads();
    for (int idx = t; idx < T1 * BB; idx += 1024) {
        int i = idx >> 6, b = idx & 63;
        int node = trace[b * TT + i + 1];
        atomicAdd(&cnt[node], 1);
    }
    __syncthreads();
    int s0 = 0;
    if (t < 256) {
#pragma unroll
        for (int j = 0; j < 8; j++) { int idx = t * 8 + j; if (idx < NNODE + 1) s0 += cnt[idx]; }
        part[t] = s0;
    }
    __syncthreads();
    for (int off = 1; off < 256; off <<= 1) {
        int u = 0;
        if (t < 256 && t >= off) u = part[t - off];
        __syncthreads();
        if (t < 256) part[t] += u;
        __syncthreads();
    }
    if (t < 256) {
        int run = part[t] - s0;
        for (int j = 0; j < 8; j++) {
            int idx = t * 8 + j;
            if (idx < NNODE + 1) { boff[idx] = run; cur[idx] = run; run += cnt[idx]; }
        }
        if (t == 255) boff[NNODE + 1] = part[255];
    }
    __syncthreads();
    for (int idx = t; idx < T1 * BB; idx += 1024) {
        int i = idx >> 6, b = idx & 63;
        int node = trace[b * TT + i + 1];
        int pos = atomicAdd(&cur[node], 1);
        items[pos] = idx;
    }
}

// one block per expert: stream weights once for all its items (chunks of 8); ctx in bf16
__global__ __launch_bounds__(256) void k_pred2(
    const unsigned short* __restrict__ ctx16, const float* __restrict__ pw, const float* __restrict__ pb,
    const int* __restrict__ boff, const int* __restrict__ items, float* __restrict__ outs)
{
    __shared__ float cl[8][ATT];
    __shared__ float red[16][16][8];
    int e = blockIdx.x;
    int start = boff[e], end = boff[e + 1];
    if (start == end) return;
    int tid = threadIdx.x;
    int d = tid & 15, ks = tid >> 4;
    const float* w = pw + (size_t)e * ATT * DD;
    float biasv = pb[e * DD + d];
    for (int c0 = start; c0 < end; c0 += 8) {
        int cn = min(8, end - c0);
        for (int j = 0; j < cn; j++) {
            int item = items[c0 + j];
            const unsigned short* cp = ctx16 + (size_t)item * ATT;
            for (int x = tid; x < ATT; x += 256)
                cl[j][x] = bf2f(cp[x]);
        }
        __syncthreads();
        float acc[8];
#pragma unroll
        for (int j = 0; j < 8; j++) acc[j] = 0.f;
        for (int kx = ks * 80; kx < ks * 80 + 80; kx++) {
            float wv = w[kx * DD + d];
#pragma unroll
            for (int j = 0; j < 8; j++) acc[j] += cl[j][kx] * wv;
        }
#pragma unroll
        for (int j = 0; j < 8; j++) red[ks][d][j] = acc[j];
        __syncthreads();
#pragma unroll
        for (int st = 8; st >= 1; st >>= 1) {
            if (ks < st) {
#pragma unroll
                for (int j = 0; j < 8; j++) red[ks][d][j] += red[ks + st][d][j];
            }
            __syncthreads();
        }
        if (ks == 0) {
            for (int j = 0; j < cn; j++) {
                int item = items[c0 + j];
                outs[(size_t)item * DD + d] = red[0][d][j] + biasv;
            }
        }
        __syncthreads();
    }
}

extern "C" void kernel_launch(void* const* d_in, const int* in_sizes, int n_in,
                              void* d_out, int out_size, void* d_ws, size_t ws_size,
                              hipStream_t stream) {
    const float* program_emb = (const float*)d_in[0];
    const float* h0       = (const float*)d_in[1];
    const float* node_emb = (const float*)d_in[2];
    const float* label_emb= (const float*)d_in[3];
    const float* w_ih     = (const float*)d_in[4];
    const float* w_hh     = (const float*)d_in[5];
    const float* b_ih     = (const float*)d_in[6];
    const float* b_hh     = (const float*)d_in[7];
    const float* ws1      = (const float*)d_in[8];
    const float* ws2      = (const float*)d_in[9];
    const float* pred_w   = (const float*)d_in[10];
    const float* pred_b   = (const float*)d_in[11];
    const int*   trace    = (const int*)d_in[12];
    const int*   na       = (const int*)d_in[13];

    // ---- R9/R12-proven layout (floats), UNCHANGED ----
    float*          ws      = (float*)d_ws;
    float*          store   = ws + 0;           // [0 .. 2,080,768)
    unsigned short* wihT16  = (unsigned short*)(ws + 2080768);   // dead after lgemm2
    unsigned short* ws1T16  = (unsigned short*)(ws + 2409472);   // dead after uscore
    float*          prog_t  = ws + 2803712;
    float*          node_t  = ws + 2852864;
    float*          sbuf    = ws + 4389632;
    float*          ebuf    = ws + 4430272;
    float*          rD      = ws + 4470912;
    float*          label_p = ws + 4511568;     // gsum (fused add); dead after rec10
    int*            whh8q   = (int*)(ws + 12834640);   // dead after rec10
    float*          wsc     = ws + 12883792;           // dead after rec10
    unsigned short* ctx16   = (unsigned short*)(ws + 4511568);   // aliases label_p (post-rec)
    int*            cnt_    = (int*)(ws + 2080768);    // over dead wihT16 (post-lgemm2)
    int*            boff    = cnt_ + 4096;
    int*            items   = boff + 2048;

    float* outs = (float*)d_out;
    float* alph = outs + T1 * BB * DD;

    // P1: static precompute (merged prep: tcvt w_ih + ws1, quant w_hh)
    k_prep<<<3016, 256, 0, stream>>>(w_ih, wihT16, ws1, ws1T16, w_hh, whh8q, wsc);
    k_mgemm<<<12,   256, 0, stream>>>(program_emb, wihT16, prog_t, b_ih,   nullptr, nullptr, 0, 64,   256, G3,  256, 12, 300, G3, 0);
    k_mgemm<<<384,  256, 0, stream>>>(node_emb,    wihT16, node_t, nullptr, nullptr, nullptr, 0, 2001, 300, G3,  300, 12, 556, G3, 0);
    k_lgemm2<<<508, 256, 0, stream>>>(label_emb, wihT16, node_t, prog_t, trace, na, label_p);

    // P2: sequential recurrence — int8 weights (R15/R16-proven rec10)
    rec10_kernel<<<64, 512, 0, stream>>>(h0, whh8q, wsc, b_hh, label_p, store);

    // P3: parallel attention + prediction
    k_uscore<<<127, 256, 0, stream>>>(store, ws1T16, ws2, sbuf);
    k_softmax_par<<<BB * NHEADS, 128, 0, stream>>>(sbuf, ebuf, rD);
    k_alphas<<<20162, 256, 0, stream>>>(ebuf, rD, alph);
    k_ctx<<<320, 256, 0, stream>>>(ebuf, rD, store, ctx16);

    // fused expert bucketing + prediction
    k_bucket<<<1, 1024, 0, stream>>>(trace, boff, items);
    k_pred2<<<NNODE + 1, 256, 0, stream>>>(ctx16, pred_w, pred_b, boff, items, outs);
}